// Round 7
// baseline (1347.158 us; speedup 1.0000x reference)
//
#include <hip/hip_runtime.h>
#include <hip/hip_cooperative_groups.h>
#include <math.h>

namespace cg = cooperative_groups;

#define GRID 768
#define NTHR 256
#define SMEM_BYTES 15876  // max stage LDS: attn1 table 3969*4 (comb 14336 fits under)

#define SC5  0.44721359549996f
#define SC10 0.31622776601684f
#define SC21 0.21821789023599f

struct Params {
    const float *x;
    const float *c1w, *c1b, *q1w, *q1b, *o1w, *o1b, *r1;
    const float *c2w, *c2b, *q2w, *q2b, *o2w, *o2b, *r2;
    const float *c3w, *c3b, *q3w, *q3b, *o3w, *o3b, *r3;
    const float *cw, *cb;
    float *out;
    float *Z0, *Z1, *Q, *K, *V, *O;
};

// ---------- 3x3 stride-2 pad-1 conv + bias + relu (grid-stride) ----------
__device__ __forceinline__ void conv_stage(const float* __restrict__ in, const float* __restrict__ w,
                                           const float* __restrict__ bias, float* __restrict__ out,
                                           int B, int Cin, int Hin, int Cout, int Hout) {
    int total = B * Cout * Hout * Hout;
    for (int t = blockIdx.x * NTHR + threadIdx.x; t < total; t += GRID * NTHR) {
        int wo = t % Hout;
        int ho = (t / Hout) % Hout;
        int co = (t / (Hout * Hout)) % Cout;
        int b  = t / (Hout * Hout * Cout);
        float acc = bias[co];
        for (int ci = 0; ci < Cin; ++ci) {
            const float* ip = in + (size_t)(b * Cin + ci) * Hin * Hin;
            const float* wp = w + (size_t)(co * Cin + ci) * 9;
            #pragma unroll
            for (int kh = 0; kh < 3; ++kh) {
                int hi = 2 * ho + kh - 1;
                if (hi < 0 || hi >= Hin) continue;
                #pragma unroll
                for (int kw = 0; kw < 3; ++kw) {
                    int wi = 2 * wo + kw - 1;
                    if (wi < 0 || wi >= Hin) continue;
                    acc = fmaf(wp[kh * 3 + kw], ip[hi * Hin + wi], acc);
                }
            }
        }
        out[t] = fmaxf(acc, 0.f);
    }
}

// ---------- qkv projection (grid-stride), padded [bh][n][DP] output ----------
__device__ __forceinline__ void qkv_stage(const float* __restrict__ z, const float* __restrict__ w,
                                          const float* __restrict__ bias, float* __restrict__ q,
                                          float* __restrict__ k, float* __restrict__ v,
                                          int B, int C, int N, int inner, int DP) {
    int total = B * N * 3 * inner;
    for (int t = blockIdx.x * NTHR + threadIdx.x; t < total; t += GRID * NTHR) {
        int n  = t % N;
        int oc = (t / N) % (3 * inner);
        int b  = t / (N * 3 * inner);
        float val = bias[oc];
        const float* zp = z + (size_t)b * C * N + n;
        const float* wp = w + (size_t)oc * C;
        #pragma unroll 8
        for (int c = 0; c < C; ++c) val = fmaf(wp[c], zp[(size_t)c * N], val);
        int part = oc / inner;
        int r = oc - part * inner;
        int hh = r % 3;   // heads fastest
        int dd = r / 3;
        float* dst = part == 0 ? q : (part == 1 ? k : v);
        dst[((size_t)(b * 3 + hh) * N + n) * DP + dd] = val;
    }
}

// ---------- attention stage (L1/L2): no-max softmax, PF-deep K/V register prefetch ----------
template <int D, int DP, int RPT, int PF>
__device__ void attn_stage(const float* __restrict__ q, const float* __restrict__ k,
                           const float* __restrict__ v, const float* __restrict__ table,
                           float* __restrict__ o, int N, int log2Hg, int T, float scale,
                           int units, float* smem) {
    if ((int)blockIdx.x >= units) return;
    float* tb = smem;    // T floats, pre-scaled
    float* comb = smem;  // overlays tb after j-loop
    constexpr int ROWS = 64 * RPT;
    constexpr int CSTR = (D % 2 == 0) ? (D + 3) : (D + 2);  // odd stride
    constexpr int NV4 = DP / 4;

    const int bh = blockIdx.x % 96;
    const int chunk = blockIdx.x / 96;
    const int h = bh % 3;
    const int tid = threadIdx.x;
    const int wave = tid >> 6;
    const int lane = tid & 63;
    const int Hg = 1 << log2Hg;
    const int W2 = 2 * Hg - 1;
    const int base = chunk * ROWS;

    for (int t = tid; t < T; t += NTHR) tb[t] = table[t * 3 + h] * scale;

    float qr[RPT][D];
    int ibase[RPT];
    #pragma unroll
    for (int r = 0; r < RPT; ++r) {
        int i = base + lane + 64 * r;
        const float* qg = q + ((size_t)bh * N + i) * DP;
        #pragma unroll
        for (int dd = 0; dd < D; ++dd) qr[r][dd] = qg[dd];
        ibase[r] = ((i >> log2Hg) + Hg - 1) * W2 + (i & (Hg - 1)) + Hg - 1;
    }
    __syncthreads();

    float acc[RPT][D];
    float lsum[RPT];
    #pragma unroll
    for (int r = 0; r < RPT; ++r) {
        lsum[r] = 0.f;
        #pragma unroll
        for (int dd = 0; dd < D; ++dd) acc[r][dd] = 0.f;
    }

    const float4* kb = (const float4*)(k + (size_t)bh * N * DP);
    const float4* vb = (const float4*)(v + (size_t)bh * N * DP);
    const int NJ = N >> 2;
    const int j0 = wave * NJ;

    float4 kbuf[PF][NV4], vbuf[PF][NV4];
    #pragma unroll
    for (int p = 0; p < PF; ++p)
        #pragma unroll
        for (int x = 0; x < NV4; ++x) {
            kbuf[p][x] = kb[(size_t)(j0 + p) * NV4 + x];
            vbuf[p][x] = vb[(size_t)(j0 + p) * NV4 + x];
        }

    for (int jj = 0; jj < NJ; jj += PF) {
        #pragma unroll
        for (int p = 0; p < PF; ++p) {
            const int j = j0 + jj + p;
            const float* kr = (const float*)&kbuf[p][0];
            const float* vr = (const float*)&vbuf[p][0];
            const int joff = (j >> log2Hg) * W2 + (j & (Hg - 1));
            #pragma unroll
            for (int r = 0; r < RPT; ++r) {
                float s = 0.f;
                #pragma unroll
                for (int dd = 0; dd < D; ++dd) s = fmaf(qr[r][dd], kr[dd], s);
                float e = __expf(fmaf(s, scale, tb[ibase[r] - joff]));
                lsum[r] += e;
                #pragma unroll
                for (int dd = 0; dd < D; ++dd) acc[r][dd] = fmaf(e, vr[dd], acc[r][dd]);
            }
            // refill slot p with row j+PF (benign over-read; stays inside workspace)
            #pragma unroll
            for (int x = 0; x < NV4; ++x) {
                kbuf[p][x] = kb[(size_t)(j + PF) * NV4 + x];
                vbuf[p][x] = vb[(size_t)(j + PF) * NV4 + x];
            }
        }
    }

    __syncthreads();
    #pragma unroll
    for (int r = 0; r < RPT; ++r) {
        float* cp = comb + (size_t)(wave * ROWS + lane + 64 * r) * CSTR;
        #pragma unroll
        for (int dd = 0; dd < D; ++dd) cp[dd] = acc[r][dd];
        cp[D] = lsum[r];
    }
    __syncthreads();
    if (tid < ROWS) {
        float af[D];
        #pragma unroll
        for (int dd = 0; dd < D; ++dd) af[dd] = 0.f;
        float lf = 0.f;
        #pragma unroll
        for (int wv = 0; wv < 4; ++wv) {
            const float* cp = comb + (size_t)(wv * ROWS + tid) * CSTR;
            #pragma unroll
            for (int dd = 0; dd < D; ++dd) af[dd] += cp[dd];
            lf += cp[D];
        }
        float inv = 1.0f / lf;
        int i = base + tid;
        #pragma unroll
        for (int dd = 0; dd < D; ++dd)
            o[((size_t)bh * D + dd) * N + i] = af[dd] * inv;  // O layout [bh][d][N]
    }
}

// ---------- L3 attention: N=64 -> one wave per bh, one lane per row; no combine ----------
__device__ void attn3_small(const float* __restrict__ q, const float* __restrict__ k,
                            const float* __restrict__ v, const float* __restrict__ table,
                            float* __restrict__ o, float scale, float* smem) {
    if ((int)blockIdx.x >= 24) return;  // 24 blocks * 4 waves = 96 bh
    constexpr int D = 21, DP = 24, NN = 64, NV4 = DP / 4;
    const int tid = threadIdx.x;
    const int wave = tid >> 6, lane = tid & 63;
    const int bh = (blockIdx.x << 2) | wave;
    const int h = bh % 3;
    float* tbw = smem + wave * 225;
    for (int t = lane; t < 225; t += 64) tbw[t] = table[t * 3 + h] * scale;
    __syncthreads();

    const int i = lane;
    const float* qg = q + ((size_t)bh * NN + i) * DP;
    float qr[D];
    #pragma unroll
    for (int dd = 0; dd < D; ++dd) qr[dd] = qg[dd];
    const int ibase = ((i >> 3) + 7) * 15 + (i & 7) + 7;

    float acc[D];
    #pragma unroll
    for (int dd = 0; dd < D; ++dd) acc[dd] = 0.f;
    float lsum = 0.f;

    const float4* kb = (const float4*)(k + (size_t)bh * NN * DP);
    const float4* vb = (const float4*)(v + (size_t)bh * NN * DP);
    #pragma unroll 2
    for (int j = 0; j < NN; ++j) {
        float4 kr4[NV4], vr4[NV4];
        #pragma unroll
        for (int x = 0; x < NV4; ++x) { kr4[x] = kb[j * NV4 + x]; vr4[x] = vb[j * NV4 + x]; }
        const float* kr = (const float*)kr4;
        const float* vr = (const float*)vr4;
        const int joff = (j >> 3) * 15 + (j & 7);
        float s = 0.f;
        #pragma unroll
        for (int dd = 0; dd < D; ++dd) s = fmaf(qr[dd], kr[dd], s);
        float e = __expf(fmaf(s, scale, tbw[ibase - joff]));
        lsum += e;
        #pragma unroll
        for (int dd = 0; dd < D; ++dd) acc[dd] = fmaf(e, vr[dd], acc[dd]);
    }
    float inv = 1.0f / lsum;
    #pragma unroll
    for (int dd = 0; dd < D; ++dd)
        o[((size_t)bh * D + dd) * NN + i] = acc[dd] * inv;
}

// ---------- output projection + bias + residual (grid-stride); o layout [bh][d][N] ----------
__device__ __forceinline__ void outproj_stage(const float* __restrict__ o, const float* __restrict__ w,
                                              const float* __restrict__ bias, const float* __restrict__ zin,
                                              float* __restrict__ zout, int B, int dim, int inner,
                                              int N, int d) {
    int total = B * dim * N;
    for (int t = blockIdx.x * NTHR + threadIdx.x; t < total; t += GRID * NTHR) {
        int n = t % N;
        int c = (t / N) % dim;
        int b = t / (N * dim);
        float val = bias[c] + zin[t];
        const float* wp = w + (size_t)c * inner;
        for (int dd = 0; dd < d; ++dd) {
            #pragma unroll
            for (int hh = 0; hh < 3; ++hh) {
                val = fmaf(wp[dd * 3 + hh], o[((size_t)((b * 3 + hh) * d) + dd) * N + n], val);
            }
        }
        zout[t] = val;
    }
}

// ---------- fused global avg pool + classifier ----------
__device__ void pool_cls_stage(const float* __restrict__ z, const float* __restrict__ w,
                               const float* __restrict__ bias, float* __restrict__ out, float* smem) {
    if (blockIdx.x >= 32) return;
    float* p = smem;
    int b = blockIdx.x;
    int c = threadIdx.x;
    if (c < 64) {
        const float* zp = z + ((size_t)b * 64 + c) * 64;
        float s = 0.f;
        #pragma unroll
        for (int n = 0; n < 64; ++n) s += zp[n];
        s *= (1.0f / 64.0f);
        p[c] = s;
        out[b * 64 + c] = s;
    }
    __syncthreads();
    if (c < 10) {
        float val = bias[c];
        const float* wp = w + (size_t)c * 64;
        #pragma unroll
        for (int kk = 0; kk < 64; ++kk) val = fmaf(wp[kk], p[kk], val);
        out[2048 + b * 10 + c] = val;
    }
}

// ---------- the mega-kernel: 13 stages, 12 grid syncs ----------
__global__ void __launch_bounds__(NTHR, 3) mega(Params p) {
    cg::grid_group grid = cg::this_grid();
    extern __shared__ float smem[];

    conv_stage(p.x, p.c1w, p.c1b, p.Z0, 32, 1, 64, 16, 32);
    grid.sync();
    qkv_stage(p.Z0, p.q1w, p.q1b, p.Q, p.K, p.V, 32, 16, 1024, 15, 8);
    grid.sync();
    attn_stage<5, 8, 2, 2>(p.Q, p.K, p.V, p.r1, p.O, 1024, 5, 3969, SC5, 768, smem);
    grid.sync();
    outproj_stage(p.O, p.o1w, p.o1b, p.Z0, p.Z1, 32, 16, 15, 1024, 5);
    grid.sync();
    conv_stage(p.Z1, p.c2w, p.c2b, p.Z0, 32, 16, 32, 32, 16);
    grid.sync();
    qkv_stage(p.Z0, p.q2w, p.q2b, p.Q, p.K, p.V, 32, 32, 256, 30, 12);
    grid.sync();
    attn_stage<10, 12, 1, 2>(p.Q, p.K, p.V, p.r2, p.O, 256, 4, 961, SC10, 384, smem);
    grid.sync();
    outproj_stage(p.O, p.o2w, p.o2b, p.Z0, p.Z1, 32, 32, 30, 256, 10);
    grid.sync();
    conv_stage(p.Z1, p.c3w, p.c3b, p.Z0, 32, 32, 16, 64, 8);
    grid.sync();
    qkv_stage(p.Z0, p.q3w, p.q3b, p.Q, p.K, p.V, 32, 64, 64, 63, 24);
    grid.sync();
    attn3_small(p.Q, p.K, p.V, p.r3, p.O, SC21, smem);
    grid.sync();
    outproj_stage(p.O, p.o3w, p.o3b, p.Z0, p.Z1, 32, 64, 63, 64, 21);
    grid.sync();
    pool_cls_stage(p.Z1, p.cw, p.cb, p.out, smem);
}

// ---------- fallback wrappers (round-5-style 13-launch path) ----------
__global__ void __launch_bounds__(NTHR) k_conv(const float* in, const float* w, const float* b,
                                               float* out, int B, int Cin, int Hin, int Cout, int Hout) {
    conv_stage(in, w, b, out, B, Cin, Hin, Cout, Hout);
}
__global__ void __launch_bounds__(NTHR) k_qkv(const float* z, const float* w, const float* b,
                                              float* q, float* k, float* v, int B, int C, int N,
                                              int inner, int DP) {
    qkv_stage(z, w, b, q, k, v, B, C, N, inner, DP);
}
__global__ void __launch_bounds__(NTHR) k_attn1(const float* q, const float* k, const float* v,
                                                const float* t, float* o) {
    extern __shared__ float s[];
    attn_stage<5, 8, 2, 2>(q, k, v, t, o, 1024, 5, 3969, SC5, 768, s);
}
__global__ void __launch_bounds__(NTHR) k_attn2(const float* q, const float* k, const float* v,
                                                const float* t, float* o) {
    extern __shared__ float s[];
    attn_stage<10, 12, 1, 2>(q, k, v, t, o, 256, 4, 961, SC10, 384, s);
}
__global__ void __launch_bounds__(NTHR) k_attn3(const float* q, const float* k, const float* v,
                                                const float* t, float* o) {
    extern __shared__ float s[];
    attn3_small(q, k, v, t, o, SC21, s);
}
__global__ void __launch_bounds__(NTHR) k_outproj(const float* o, const float* w, const float* b,
                                                  const float* zin, float* zout, int B, int dim,
                                                  int inner, int N, int d) {
    outproj_stage(o, w, b, zin, zout, B, dim, inner, N, d);
}
__global__ void __launch_bounds__(NTHR) k_poolcls(const float* z, const float* w, const float* b,
                                                  float* out) {
    extern __shared__ float s[];
    pool_cls_stage(z, w, b, out, s);
}

extern "C" void kernel_launch(void* const* d_in, const int* in_sizes, int n_in,
                              void* d_out, int out_size, void* d_ws, size_t ws_size,
                              hipStream_t stream) {
    float* ws = (float*)d_ws;
    Params p;
    p.x   = (const float*)d_in[0];
    p.c1w = (const float*)d_in[1];  p.c1b = (const float*)d_in[2];
    p.q1w = (const float*)d_in[3];  p.q1b = (const float*)d_in[4];
    p.o1w = (const float*)d_in[5];  p.o1b = (const float*)d_in[6];
    p.r1  = (const float*)d_in[7];
    p.c2w = (const float*)d_in[8];  p.c2b = (const float*)d_in[9];
    p.q2w = (const float*)d_in[10]; p.q2b = (const float*)d_in[11];
    p.o2w = (const float*)d_in[12]; p.o2b = (const float*)d_in[13];
    p.r2  = (const float*)d_in[14];
    p.c3w = (const float*)d_in[15]; p.c3b = (const float*)d_in[16];
    p.q3w = (const float*)d_in[17]; p.q3b = (const float*)d_in[18];
    p.o3w = (const float*)d_in[19]; p.o3b = (const float*)d_in[20];
    p.r3  = (const float*)d_in[21];
    p.cw  = (const float*)d_in[22]; p.cb  = (const float*)d_in[23];
    p.out = (float*)d_out;
    p.Z0 = ws;                 // 524288 floats
    p.Z1 = p.Z0 + 524288;      // 524288
    p.Q  = p.Z1 + 524288;      // 786432 (96*1024*8 max)
    p.K  = p.Q + 786432;
    p.V  = p.K + 786432;
    p.O  = p.V + 786432;       // 491520

    void* args[] = {(void*)&p};
    hipError_t err = hipLaunchCooperativeKernel((void*)mega, dim3(GRID), dim3(NTHR), args,
                                                SMEM_BYTES, stream);
    if (err != hipSuccess) {
        (void)hipGetLastError();  // clear sticky error; run the 13-launch fallback
        k_conv<<<GRID, NTHR, 0, stream>>>(p.x, p.c1w, p.c1b, p.Z0, 32, 1, 64, 16, 32);
        k_qkv<<<GRID, NTHR, 0, stream>>>(p.Z0, p.q1w, p.q1b, p.Q, p.K, p.V, 32, 16, 1024, 15, 8);
        k_attn1<<<768, NTHR, SMEM_BYTES, stream>>>(p.Q, p.K, p.V, p.r1, p.O);
        k_outproj<<<GRID, NTHR, 0, stream>>>(p.O, p.o1w, p.o1b, p.Z0, p.Z1, 32, 16, 15, 1024, 5);
        k_conv<<<GRID, NTHR, 0, stream>>>(p.Z1, p.c2w, p.c2b, p.Z0, 32, 16, 32, 32, 16);
        k_qkv<<<GRID, NTHR, 0, stream>>>(p.Z0, p.q2w, p.q2b, p.Q, p.K, p.V, 32, 32, 256, 30, 12);
        k_attn2<<<384, NTHR, 13312, stream>>>(p.Q, p.K, p.V, p.r2, p.O);
        k_outproj<<<GRID, NTHR, 0, stream>>>(p.O, p.o2w, p.o2b, p.Z0, p.Z1, 32, 32, 30, 256, 10);
        k_conv<<<GRID, NTHR, 0, stream>>>(p.Z1, p.c3w, p.c3b, p.Z0, 32, 32, 16, 64, 8);
        k_qkv<<<GRID, NTHR, 0, stream>>>(p.Z0, p.q3w, p.q3b, p.Q, p.K, p.V, 32, 64, 64, 63, 24);
        k_attn3<<<24, NTHR, 3600, stream>>>(p.Q, p.K, p.V, p.r3, p.O);
        k_outproj<<<GRID, NTHR, 0, stream>>>(p.O, p.o3w, p.o3b, p.Z0, p.Z1, 32, 64, 63, 64, 21);
        k_poolcls<<<32, NTHR, 256, stream>>>(p.Z1, p.cw, p.cb, p.out);
    }
}

// Round 8
// 434.241 us; speedup vs baseline: 3.1023x; 3.1023x over previous
//
#include <hip/hip_runtime.h>
#include <math.h>

#define CDIV(a, b) (((a) + (b) - 1) / (b))

#define SC5  0.44721359549996f
#define SC10 0.31622776601684f
#define SC21 0.21821789023599f

// ---------- fused 3x3 s2 conv + relu + qkv projection ----------
// block handles TPX pixels of one batch: conv -> LDS + global z, then qkv from LDS.
// qkv written padded [bh][n][DP], heads-fastest channel split.
template <int CIN, int HIN, int COUT, int HOUT, int INNER, int DP, int TPX>
__global__ void __launch_bounds__(256) conv_qkv(const float* __restrict__ in,
                                                const float* __restrict__ cw,
                                                const float* __restrict__ cb,
                                                const float* __restrict__ qw,
                                                const float* __restrict__ qb,
                                                float* __restrict__ z, float* __restrict__ q,
                                                float* __restrict__ k, float* __restrict__ v) {
    constexpr int N = HOUT * HOUT;
    __shared__ float zt[COUT * TPX];
    const int b  = blockIdx.x / (N / TPX);
    const int n0 = (blockIdx.x % (N / TPX)) * TPX;
    const int tid = threadIdx.x;

    // phase 1: conv outputs for this tile (c-major, px fastest -> coalesced z writes)
    for (int idx = tid; idx < COUT * TPX; idx += 256) {
        int c = idx / TPX, px = idx % TPX;
        int n = n0 + px;
        int ho = n / HOUT, wo = n % HOUT;
        float acc = cb[c];
        for (int ci = 0; ci < CIN; ++ci) {
            const float* ip = in + (size_t)(b * CIN + ci) * HIN * HIN;
            const float* wp = cw + (size_t)(c * CIN + ci) * 9;
            #pragma unroll
            for (int kh = 0; kh < 3; ++kh) {
                int hi = 2 * ho + kh - 1;
                if (hi < 0 || hi >= HIN) continue;
                #pragma unroll
                for (int kw = 0; kw < 3; ++kw) {
                    int wi = 2 * wo + kw - 1;
                    if (wi < 0 || wi >= HIN) continue;
                    acc = fmaf(wp[kh * 3 + kw], ip[hi * HIN + wi], acc);
                }
            }
        }
        acc = fmaxf(acc, 0.f);
        zt[idx] = acc;
        z[((size_t)(b * COUT) + c) * N + n] = acc;
    }
    __syncthreads();

    // phase 2: qkv from LDS tile (w reads wave-uniform -> scalar loads)
    constexpr int OC3 = 3 * INNER;
    for (int idx = tid; idx < OC3 * TPX; idx += 256) {
        int oc = idx / TPX, px = idx % TPX;
        float val = qb[oc];
        const float* wp = qw + (size_t)oc * COUT;
        #pragma unroll 8
        for (int c = 0; c < COUT; ++c) val = fmaf(wp[c], zt[c * TPX + px], val);
        int part = oc / INNER;
        int r = oc - part * INNER;
        int hh = r % 3, dd = r / 3;  // heads fastest
        float* dst = part == 0 ? q : (part == 1 ? k : v);
        dst[((size_t)(b * 3 + hh) * N + n0 + px) * DP + dd] = val;
    }
}

// ---------- attention (L1/L2): no-max softmax, PF-deep K/V register prefetch ----------
// grid = 96*IC (bh = blockIdx%96); 4-wave j-split; RPT rows/thread; LDS combine (odd stride).
template <int D, int DP, int RPT, int PF>
__global__ void __launch_bounds__(256) attn_big(const float* __restrict__ q,
                                                const float* __restrict__ k,
                                                const float* __restrict__ v,
                                                const float* __restrict__ table,
                                                float* __restrict__ o, int N, int log2Hg,
                                                int T, float scale) {
    extern __shared__ float smem[];
    float* tb = smem;    // T floats, pre-scaled
    float* comb = smem;  // overlays tb after j-loop
    constexpr int ROWS = 64 * RPT;
    constexpr int CSTR = (D % 2 == 0) ? (D + 3) : (D + 2);
    constexpr int NV4 = DP / 4;

    const int bh = blockIdx.x % 96;
    const int chunk = blockIdx.x / 96;
    const int h = bh % 3;
    const int tid = threadIdx.x;
    const int wave = tid >> 6;
    const int lane = tid & 63;
    const int Hg = 1 << log2Hg;
    const int W2 = 2 * Hg - 1;
    const int base = chunk * ROWS;

    for (int t = tid; t < T; t += 256) tb[t] = table[t * 3 + h] * scale;

    float qr[RPT][D];
    int ibase[RPT];
    #pragma unroll
    for (int r = 0; r < RPT; ++r) {
        int i = base + lane + 64 * r;
        const float* qg = q + ((size_t)bh * N + i) * DP;
        #pragma unroll
        for (int dd = 0; dd < D; ++dd) qr[r][dd] = qg[dd];
        ibase[r] = ((i >> log2Hg) + Hg - 1) * W2 + (i & (Hg - 1)) + Hg - 1;
    }
    __syncthreads();

    float acc[RPT][D];
    float lsum[RPT];
    #pragma unroll
    for (int r = 0; r < RPT; ++r) {
        lsum[r] = 0.f;
        #pragma unroll
        for (int dd = 0; dd < D; ++dd) acc[r][dd] = 0.f;
    }

    const float4* kb = (const float4*)(k + (size_t)bh * N * DP);
    const float4* vb = (const float4*)(v + (size_t)bh * N * DP);
    const int NJ = N >> 2;
    const int j0 = wave * NJ;

    float4 kbuf[PF][NV4], vbuf[PF][NV4];
    #pragma unroll
    for (int p = 0; p < PF; ++p)
        #pragma unroll
        for (int x = 0; x < NV4; ++x) {
            kbuf[p][x] = kb[(size_t)(j0 + p) * NV4 + x];
            vbuf[p][x] = vb[(size_t)(j0 + p) * NV4 + x];
        }

    for (int jj = 0; jj < NJ; jj += PF) {
        #pragma unroll
        for (int p = 0; p < PF; ++p) {
            const int j = j0 + jj + p;
            const float* kr = (const float*)&kbuf[p][0];
            const float* vr = (const float*)&vbuf[p][0];
            const int joff = (j >> log2Hg) * W2 + (j & (Hg - 1));
            #pragma unroll
            for (int r = 0; r < RPT; ++r) {
                float s = 0.f;
                #pragma unroll
                for (int dd = 0; dd < D; ++dd) s = fmaf(qr[r][dd], kr[dd], s);
                float e = __expf(fmaf(s, scale, tb[ibase[r] - joff]));
                lsum[r] += e;
                #pragma unroll
                for (int dd = 0; dd < D; ++dd) acc[r][dd] = fmaf(e, vr[dd], acc[r][dd]);
            }
            // refill slot p (benign over-read; stays inside workspace)
            #pragma unroll
            for (int x = 0; x < NV4; ++x) {
                kbuf[p][x] = kb[(size_t)(j + PF) * NV4 + x];
                vbuf[p][x] = vb[(size_t)(j + PF) * NV4 + x];
            }
        }
    }

    __syncthreads();
    #pragma unroll
    for (int r = 0; r < RPT; ++r) {
        float* cp = comb + (size_t)(wave * ROWS + lane + 64 * r) * CSTR;
        #pragma unroll
        for (int dd = 0; dd < D; ++dd) cp[dd] = acc[r][dd];
        cp[D] = lsum[r];
    }
    __syncthreads();
    if (tid < ROWS) {
        float af[D];
        #pragma unroll
        for (int dd = 0; dd < D; ++dd) af[dd] = 0.f;
        float lf = 0.f;
        #pragma unroll
        for (int wv = 0; wv < 4; ++wv) {
            const float* cp = comb + (size_t)(wv * ROWS + tid) * CSTR;
            #pragma unroll
            for (int dd = 0; dd < D; ++dd) af[dd] += cp[dd];
            lf += cp[D];
        }
        float inv = 1.0f / lf;
        int i = base + tid;
        #pragma unroll
        for (int dd = 0; dd < D; ++dd)
            o[((size_t)bh * D + dd) * N + i] = af[dd] * inv;  // O layout [bh][d][N]
    }
}

// ---------- L3 attention: N=64 -> one wave per bh, one lane per row ----------
__global__ void __launch_bounds__(256) attn_small(const float* __restrict__ q,
                                                  const float* __restrict__ k,
                                                  const float* __restrict__ v,
                                                  const float* __restrict__ table,
                                                  float* __restrict__ o, float scale) {
    __shared__ float smem[4 * 225];
    constexpr int D = 21, DP = 24, NN = 64, NV4 = DP / 4;
    const int tid = threadIdx.x;
    const int wave = tid >> 6, lane = tid & 63;
    const int bh = (blockIdx.x << 2) | wave;
    const int h = bh % 3;
    float* tbw = smem + wave * 225;
    for (int t = lane; t < 225; t += 64) tbw[t] = table[t * 3 + h] * scale;
    __syncthreads();

    const int i = lane;
    const float* qg = q + ((size_t)bh * NN + i) * DP;
    float qr[D];
    #pragma unroll
    for (int dd = 0; dd < D; ++dd) qr[dd] = qg[dd];
    const int ibase = ((i >> 3) + 7) * 15 + (i & 7) + 7;

    float acc[D];
    #pragma unroll
    for (int dd = 0; dd < D; ++dd) acc[dd] = 0.f;
    float lsum = 0.f;

    const float4* kb = (const float4*)(k + (size_t)bh * NN * DP);
    const float4* vb = (const float4*)(v + (size_t)bh * NN * DP);
    #pragma unroll 2
    for (int j = 0; j < NN; ++j) {
        float4 kr4[NV4], vr4[NV4];
        #pragma unroll
        for (int x = 0; x < NV4; ++x) { kr4[x] = kb[j * NV4 + x]; vr4[x] = vb[j * NV4 + x]; }
        const float* kr = (const float*)kr4;
        const float* vr = (const float*)vr4;
        const int joff = (j >> 3) * 15 + (j & 7);
        float s = 0.f;
        #pragma unroll
        for (int dd = 0; dd < D; ++dd) s = fmaf(qr[dd], kr[dd], s);
        float e = __expf(fmaf(s, scale, tbw[ibase - joff]));
        lsum += e;
        #pragma unroll
        for (int dd = 0; dd < D; ++dd) acc[dd] = fmaf(e, vr[dd], acc[dd]);
    }
    float inv = 1.0f / lsum;
    #pragma unroll
    for (int dd = 0; dd < D; ++dd)
        o[((size_t)bh * D + dd) * NN + i] = acc[dd] * inv;
}

// ---------- output projection + bias + residual (exact grid); o layout [bh][d][N] ----------
__global__ void __launch_bounds__(256) outproj(const float* __restrict__ o,
                                               const float* __restrict__ w,
                                               const float* __restrict__ bias,
                                               const float* __restrict__ zin,
                                               float* __restrict__ zout,
                                               int dim, int inner, int N, int d) {
    int t = blockIdx.x * 256 + threadIdx.x;
    int n = t % N;
    int c = (t / N) % dim;
    int b = t / (N * dim);
    float val = bias[c] + zin[t];
    const float* wp = w + (size_t)c * inner;
    for (int dd = 0; dd < d; ++dd) {
        #pragma unroll
        for (int hh = 0; hh < 3; ++hh) {
            val = fmaf(wp[dd * 3 + hh], o[((size_t)((b * 3 + hh) * d) + dd) * N + n], val);
        }
    }
    zout[t] = val;
}

// ---------- tail: outproj3 + global-avg-pool + classifier, one block per batch ----------
__global__ void __launch_bounds__(256) tail(const float* __restrict__ o,
                                            const float* __restrict__ ow,
                                            const float* __restrict__ ob,
                                            const float* __restrict__ zin,
                                            const float* __restrict__ cw,
                                            const float* __restrict__ cb,
                                            float* __restrict__ out) {
    __shared__ float zt[64 * 65];
    __shared__ float p[64];
    const int b = blockIdx.x;
    const int tid = threadIdx.x;
    for (int idx = tid; idx < 64 * 64; idx += 256) {
        int c = idx >> 6, n = idx & 63;
        float val = ob[c] + zin[((size_t)(b * 64) + c) * 64 + n];
        const float* wp = ow + (size_t)c * 63;
        for (int dd = 0; dd < 21; ++dd) {
            #pragma unroll
            for (int hh = 0; hh < 3; ++hh)
                val = fmaf(wp[dd * 3 + hh], o[((size_t)((b * 3 + hh) * 21) + dd) * 64 + n], val);
        }
        zt[c * 65 + n] = val;
    }
    __syncthreads();
    if (tid < 64) {
        float s = 0.f;
        #pragma unroll
        for (int n = 0; n < 64; ++n) s += zt[tid * 65 + n];
        s *= (1.0f / 64.0f);
        p[tid] = s;
        out[b * 64 + tid] = s;
    }
    __syncthreads();
    if (tid < 10) {
        float val = cb[tid];
        const float* wp = cw + (size_t)tid * 64;
        #pragma unroll
        for (int kk = 0; kk < 64; ++kk) val = fmaf(wp[kk], p[kk], val);
        out[2048 + b * 10 + tid] = val;
    }
}

extern "C" void kernel_launch(void* const* d_in, const int* in_sizes, int n_in,
                              void* d_out, int out_size, void* d_ws, size_t ws_size,
                              hipStream_t stream) {
    float* ws = (float*)d_ws;
    float* Z0 = ws;                // conv z (residual input)
    float* Z1 = Z0 + 524288;       // outproj result / next conv input
    float* Q  = Z1 + 524288;       // 786432 (96*1024*8 max)
    float* K  = Q + 786432;
    float* V  = K + 786432;
    float* O  = V + 786432;        // 491520

    float* out = (float*)d_out;

    // ===== layer 1: Cin=1 H64->32, dim=16, inner=15, d=5 (DP=8), N=1024, Hg=32 =====
    conv_qkv<1, 64, 16, 32, 15, 8, 64><<<32 * 16, 256, 0, stream>>>(
        (const float*)d_in[0], (const float*)d_in[1], (const float*)d_in[2],
        (const float*)d_in[3], (const float*)d_in[4], Z0, Q, K, V);
    attn_big<5, 8, 2, 2><<<96 * 8, 256, 15876, stream>>>(
        Q, K, V, (const float*)d_in[7], O, 1024, 5, 3969, SC5);
    outproj<<<2048, 256, 0, stream>>>(
        O, (const float*)d_in[5], (const float*)d_in[6], Z0, Z1, 16, 15, 1024, 5);

    // ===== layer 2: Cin=16 H32->16, dim=32, inner=30, d=10 (DP=12), N=256, Hg=16 =====
    conv_qkv<16, 32, 32, 16, 30, 12, 32><<<32 * 8, 256, 0, stream>>>(
        Z1, (const float*)d_in[8], (const float*)d_in[9],
        (const float*)d_in[10], (const float*)d_in[11], Z0, Q, K, V);
    attn_big<10, 12, 1, 2><<<96 * 4, 256, 13312, stream>>>(
        Q, K, V, (const float*)d_in[14], O, 256, 4, 961, SC10);
    outproj<<<1024, 256, 0, stream>>>(
        O, (const float*)d_in[12], (const float*)d_in[13], Z0, Z1, 32, 30, 256, 10);

    // ===== layer 3: Cin=32 H16->8, dim=64, inner=63, d=21 (DP=24), N=64, Hg=8 =====
    conv_qkv<32, 16, 64, 8, 63, 24, 8><<<32 * 8, 256, 0, stream>>>(
        Z1, (const float*)d_in[15], (const float*)d_in[16],
        (const float*)d_in[17], (const float*)d_in[18], Z0, Q, K, V);
    attn_small<<<24, 256, 0, stream>>>(Q, K, V, (const float*)d_in[21], O, SC21);
    tail<<<32, 256, 0, stream>>>(
        O, (const float*)d_in[19], (const float*)d_in[20], Z0,
        (const float*)d_in[22], (const float*)d_in[23], out);
}

// Round 9
// 361.017 us; speedup vs baseline: 3.7316x; 1.2028x over previous
//
#include <hip/hip_runtime.h>
#include <math.h>

#define CDIV(a, b) (((a) + (b) - 1) / (b))

#define SC5  0.44721359549996f
#define SC10 0.31622776601684f
#define SC21 0.21821789023599f

// ---------- fused 3x3 s2 conv + relu + qkv projection ----------
// block handles TPX pixels of one batch: conv -> LDS + global z, then qkv from LDS.
// qkv written padded [bh][n][DP], heads-fastest channel split.
template <int CIN, int HIN, int COUT, int HOUT, int INNER, int DP, int TPX>
__global__ void __launch_bounds__(256) conv_qkv(const float* __restrict__ in,
                                                const float* __restrict__ cw,
                                                const float* __restrict__ cb,
                                                const float* __restrict__ qw,
                                                const float* __restrict__ qb,
                                                float* __restrict__ z, float* __restrict__ q,
                                                float* __restrict__ k, float* __restrict__ v) {
    constexpr int N = HOUT * HOUT;
    __shared__ float zt[COUT * TPX];
    const int b  = blockIdx.x / (N / TPX);
    const int n0 = (blockIdx.x % (N / TPX)) * TPX;
    const int tid = threadIdx.x;

    // phase 1: conv outputs for this tile (c-major, px fastest -> coalesced z writes)
    for (int idx = tid; idx < COUT * TPX; idx += 256) {
        int c = idx / TPX, px = idx % TPX;
        int n = n0 + px;
        int ho = n / HOUT, wo = n % HOUT;
        float acc = cb[c];
        for (int ci = 0; ci < CIN; ++ci) {
            const float* ip = in + (size_t)(b * CIN + ci) * HIN * HIN;
            const float* wp = cw + (size_t)(c * CIN + ci) * 9;
            #pragma unroll
            for (int kh = 0; kh < 3; ++kh) {
                int hi = 2 * ho + kh - 1;
                if (hi < 0 || hi >= HIN) continue;
                #pragma unroll
                for (int kw = 0; kw < 3; ++kw) {
                    int wi = 2 * wo + kw - 1;
                    if (wi < 0 || wi >= HIN) continue;
                    acc = fmaf(wp[kh * 3 + kw], ip[hi * HIN + wi], acc);
                }
            }
        }
        acc = fmaxf(acc, 0.f);
        zt[idx] = acc;
        z[((size_t)(b * COUT) + c) * N + n] = acc;
    }
    __syncthreads();

    // phase 2: qkv from LDS tile (w reads wave-uniform -> scalar loads)
    constexpr int OC3 = 3 * INNER;
    for (int idx = tid; idx < OC3 * TPX; idx += 256) {
        int oc = idx / TPX, px = idx % TPX;
        float val = qb[oc];
        const float* wp = qw + (size_t)oc * COUT;
        #pragma unroll 8
        for (int c = 0; c < COUT; ++c) val = fmaf(wp[c], zt[c * TPX + px], val);
        int part = oc / INNER;
        int r = oc - part * INNER;
        int hh = r % 3, dd = r / 3;  // heads fastest
        float* dst = part == 0 ? q : (part == 1 ? k : v);
        dst[((size_t)(b * 3 + hh) * N + n0 + px) * DP + dd] = val;
    }
}

// ---------- attention (L1/L2): no-max softmax, PF-deep K/V register prefetch ----------
// grid = 96*IC (bh = blockIdx%96); 4-wave j-split; RPT rows/thread; LDS combine (odd stride).
template <int D, int DP, int RPT, int PF>
__global__ void __launch_bounds__(256) attn_big(const float* __restrict__ q,
                                                const float* __restrict__ k,
                                                const float* __restrict__ v,
                                                const float* __restrict__ table,
                                                float* __restrict__ o, int N, int log2Hg,
                                                int T, float scale) {
    extern __shared__ float smem[];
    float* tb = smem;    // T floats, pre-scaled
    float* comb = smem;  // overlays tb after j-loop
    constexpr int ROWS = 64 * RPT;
    constexpr int CSTR = (D % 2 == 0) ? (D + 3) : (D + 2);
    constexpr int NV4 = DP / 4;

    const int bh = blockIdx.x % 96;
    const int chunk = blockIdx.x / 96;
    const int h = bh % 3;
    const int tid = threadIdx.x;
    const int wave = tid >> 6;
    const int lane = tid & 63;
    const int Hg = 1 << log2Hg;
    const int W2 = 2 * Hg - 1;
    const int base = chunk * ROWS;

    for (int t = tid; t < T; t += 256) tb[t] = table[t * 3 + h] * scale;

    float qr[RPT][D];
    int ibase[RPT];
    #pragma unroll
    for (int r = 0; r < RPT; ++r) {
        int i = base + lane + 64 * r;
        const float* qg = q + ((size_t)bh * N + i) * DP;
        #pragma unroll
        for (int dd = 0; dd < D; ++dd) qr[r][dd] = qg[dd];
        ibase[r] = ((i >> log2Hg) + Hg - 1) * W2 + (i & (Hg - 1)) + Hg - 1;
    }
    __syncthreads();

    float acc[RPT][D];
    float lsum[RPT];
    #pragma unroll
    for (int r = 0; r < RPT; ++r) {
        lsum[r] = 0.f;
        #pragma unroll
        for (int dd = 0; dd < D; ++dd) acc[r][dd] = 0.f;
    }

    const float4* kb = (const float4*)(k + (size_t)bh * N * DP);
    const float4* vb = (const float4*)(v + (size_t)bh * N * DP);
    const int NJ = N >> 2;
    const int j0 = wave * NJ;

    float4 kbuf[PF][NV4], vbuf[PF][NV4];
    #pragma unroll
    for (int p = 0; p < PF; ++p)
        #pragma unroll
        for (int x = 0; x < NV4; ++x) {
            kbuf[p][x] = kb[(size_t)(j0 + p) * NV4 + x];
            vbuf[p][x] = vb[(size_t)(j0 + p) * NV4 + x];
        }

    for (int jj = 0; jj < NJ; jj += PF) {
        #pragma unroll
        for (int p = 0; p < PF; ++p) {
            const int j = j0 + jj + p;
            const float* kr = (const float*)&kbuf[p][0];
            const float* vr = (const float*)&vbuf[p][0];
            const int joff = (j >> log2Hg) * W2 + (j & (Hg - 1));
            #pragma unroll
            for (int r = 0; r < RPT; ++r) {
                float s = 0.f;
                #pragma unroll
                for (int dd = 0; dd < D; ++dd) s = fmaf(qr[r][dd], kr[dd], s);
                float e = __expf(fmaf(s, scale, tb[ibase[r] - joff]));
                lsum[r] += e;
                #pragma unroll
                for (int dd = 0; dd < D; ++dd) acc[r][dd] = fmaf(e, vr[dd], acc[r][dd]);
            }
            // refill slot p (benign over-read; stays inside workspace)
            #pragma unroll
            for (int x = 0; x < NV4; ++x) {
                kbuf[p][x] = kb[(size_t)(j + PF) * NV4 + x];
                vbuf[p][x] = vb[(size_t)(j + PF) * NV4 + x];
            }
        }
    }

    __syncthreads();
    #pragma unroll
    for (int r = 0; r < RPT; ++r) {
        float* cp = comb + (size_t)(wave * ROWS + lane + 64 * r) * CSTR;
        #pragma unroll
        for (int dd = 0; dd < D; ++dd) cp[dd] = acc[r][dd];
        cp[D] = lsum[r];
    }
    __syncthreads();
    if (tid < ROWS) {
        float af[D];
        #pragma unroll
        for (int dd = 0; dd < D; ++dd) af[dd] = 0.f;
        float lf = 0.f;
        #pragma unroll
        for (int wv = 0; wv < 4; ++wv) {
            const float* cp = comb + (size_t)(wv * ROWS + tid) * CSTR;
            #pragma unroll
            for (int dd = 0; dd < D; ++dd) af[dd] += cp[dd];
            lf += cp[D];
        }
        float inv = 1.0f / lf;
        int i = base + tid;
        #pragma unroll
        for (int dd = 0; dd < D; ++dd)
            o[((size_t)bh * D + dd) * N + i] = af[dd] * inv;  // O layout [bh][d][N]
    }
}

// ---------- L3 attention v2: one block per bh; K/V+table staged in LDS; 4-wave j-split ----------
// wave = j-quarter (16 js), lane = row. LDS broadcast K/V reads (conflict-free), LDS combine.
__global__ void __launch_bounds__(256) attn_small(const float* __restrict__ q,
                                                  const float* __restrict__ k,
                                                  const float* __restrict__ v,
                                                  const float* __restrict__ table,
                                                  float* __restrict__ o, float scale) {
    constexpr int D = 21, DP = 24, NN = 64;
    constexpr int CSTR = 23;  // odd stride for combine
    __shared__ float smem[4 * NN * CSTR];  // 23552 B; comb overlays ks/vs/tb
    float* ks = smem;              // 1536 floats
    float* vs = ks + NN * DP;      // 1536
    float* tb = vs + NN * DP;      // 225
    float* comb = smem;

    const int bh = blockIdx.x;     // 96 blocks
    const int h = bh % 3;
    const int tid = threadIdx.x;
    const int wave = tid >> 6;
    const int lane = tid & 63;

    // stage K, V (coalesced float4: 768 loads / 256 threads = 3 each) + table
    {
        const float4* kg = (const float4*)(k + (size_t)bh * NN * DP);
        const float4* vg = (const float4*)(v + (size_t)bh * NN * DP);
        float4* ks4 = (float4*)ks;
        float4* vs4 = (float4*)vs;
        for (int t = tid; t < NN * DP / 4; t += 256) { ks4[t] = kg[t]; vs4[t] = vg[t]; }
        for (int t = tid; t < 225; t += 256) tb[t] = table[t * 3 + h] * scale;
    }

    const int i = lane;  // each wave covers all 64 rows
    const float* qg = q + ((size_t)bh * NN + i) * DP;
    float qr[D];
    #pragma unroll
    for (int dd = 0; dd < D; ++dd) qr[dd] = qg[dd];
    const int ibase = ((i >> 3) + 7) * 15 + (i & 7) + 7;
    __syncthreads();

    float acc[D];
    #pragma unroll
    for (int dd = 0; dd < D; ++dd) acc[dd] = 0.f;
    float lsum = 0.f;

    const int j0 = wave * 16;
    #pragma unroll
    for (int jj = 0; jj < 16; ++jj) {
        const int j = j0 + jj;
        // wave-uniform LDS reads -> broadcast, conflict-free
        float4 kr4[6], vr4[6];
        const float4* kp = (const float4*)(ks + j * DP);
        const float4* vp = (const float4*)(vs + j * DP);
        #pragma unroll
        for (int x = 0; x < 6; ++x) { kr4[x] = kp[x]; vr4[x] = vp[x]; }
        const float* kr = (const float*)kr4;
        const float* vr = (const float*)vr4;
        const int joff = (j >> 3) * 15 + (j & 7);
        float s = 0.f;
        #pragma unroll
        for (int dd = 0; dd < D; ++dd) s = fmaf(qr[dd], kr[dd], s);
        float e = __expf(fmaf(s, scale, tb[ibase - joff]));
        lsum += e;
        #pragma unroll
        for (int dd = 0; dd < D; ++dd) acc[dd] = fmaf(e, vr[dd], acc[dd]);
    }

    __syncthreads();
    {
        float* cp = comb + (size_t)(wave * NN + lane) * CSTR;
        #pragma unroll
        for (int dd = 0; dd < D; ++dd) cp[dd] = acc[dd];
        cp[D] = lsum;
    }
    __syncthreads();
    if (tid < NN) {
        float af[D];
        #pragma unroll
        for (int dd = 0; dd < D; ++dd) af[dd] = 0.f;
        float lf = 0.f;
        #pragma unroll
        for (int wv = 0; wv < 4; ++wv) {
            const float* cp = comb + (size_t)(wv * NN + tid) * CSTR;
            #pragma unroll
            for (int dd = 0; dd < D; ++dd) af[dd] += cp[dd];
            lf += cp[D];
        }
        float inv = 1.0f / lf;
        #pragma unroll
        for (int dd = 0; dd < D; ++dd)
            o[((size_t)bh * D + dd) * NN + tid] = af[dd] * inv;
    }
}

// ---------- output projection + bias + residual (exact grid); o layout [bh][d][N] ----------
__global__ void __launch_bounds__(256) outproj(const float* __restrict__ o,
                                               const float* __restrict__ w,
                                               const float* __restrict__ bias,
                                               const float* __restrict__ zin,
                                               float* __restrict__ zout,
                                               int dim, int inner, int N, int d) {
    int t = blockIdx.x * 256 + threadIdx.x;
    int n = t % N;
    int c = (t / N) % dim;
    int b = t / (N * dim);
    float val = bias[c] + zin[t];
    const float* wp = w + (size_t)c * inner;
    for (int dd = 0; dd < d; ++dd) {
        #pragma unroll
        for (int hh = 0; hh < 3; ++hh) {
            val = fmaf(wp[dd * 3 + hh], o[((size_t)((b * 3 + hh) * d) + dd) * N + n], val);
        }
    }
    zout[t] = val;
}

// ---------- tail: outproj3 + global-avg-pool + classifier, one block per batch ----------
__global__ void __launch_bounds__(256) tail(const float* __restrict__ o,
                                            const float* __restrict__ ow,
                                            const float* __restrict__ ob,
                                            const float* __restrict__ zin,
                                            const float* __restrict__ cw,
                                            const float* __restrict__ cb,
                                            float* __restrict__ out) {
    __shared__ float zt[64 * 65];
    __shared__ float p[64];
    const int b = blockIdx.x;
    const int tid = threadIdx.x;
    for (int idx = tid; idx < 64 * 64; idx += 256) {
        int c = idx >> 6, n = idx & 63;
        float val = ob[c] + zin[((size_t)(b * 64) + c) * 64 + n];
        const float* wp = ow + (size_t)c * 63;
        for (int dd = 0; dd < 21; ++dd) {
            #pragma unroll
            for (int hh = 0; hh < 3; ++hh)
                val = fmaf(wp[dd * 3 + hh], o[((size_t)((b * 3 + hh) * 21) + dd) * 64 + n], val);
        }
        zt[c * 65 + n] = val;
    }
    __syncthreads();
    if (tid < 64) {
        float s = 0.f;
        #pragma unroll
        for (int n = 0; n < 64; ++n) s += zt[tid * 65 + n];
        s *= (1.0f / 64.0f);
        p[tid] = s;
        out[b * 64 + tid] = s;
    }
    __syncthreads();
    if (tid < 10) {
        float val = cb[tid];
        const float* wp = cw + (size_t)tid * 64;
        #pragma unroll
        for (int kk = 0; kk < 64; ++kk) val = fmaf(wp[kk], p[kk], val);
        out[2048 + b * 10 + tid] = val;
    }
}

extern "C" void kernel_launch(void* const* d_in, const int* in_sizes, int n_in,
                              void* d_out, int out_size, void* d_ws, size_t ws_size,
                              hipStream_t stream) {
    float* ws = (float*)d_ws;
    float* Z0 = ws;                // conv z (residual input)
    float* Z1 = Z0 + 524288;       // outproj result / next conv input
    float* Q  = Z1 + 524288;       // 786432 (96*1024*8 max)
    float* K  = Q + 786432;
    float* V  = K + 786432;
    float* O  = V + 786432;        // 491520

    float* out = (float*)d_out;

    // ===== layer 1: Cin=1 H64->32, dim=16, inner=15, d=5 (DP=8), N=1024, Hg=32 =====
    conv_qkv<1, 64, 16, 32, 15, 8, 64><<<32 * 16, 256, 0, stream>>>(
        (const float*)d_in[0], (const float*)d_in[1], (const float*)d_in[2],
        (const float*)d_in[3], (const float*)d_in[4], Z0, Q, K, V);
    attn_big<5, 8, 2, 2><<<96 * 8, 256, 15876, stream>>>(
        Q, K, V, (const float*)d_in[7], O, 1024, 5, 3969, SC5);
    outproj<<<2048, 256, 0, stream>>>(
        O, (const float*)d_in[5], (const float*)d_in[6], Z0, Z1, 16, 15, 1024, 5);

    // ===== layer 2: Cin=16 H32->16, dim=32, inner=30, d=10 (DP=12), N=256, Hg=16 =====
    conv_qkv<16, 32, 32, 16, 30, 12, 32><<<32 * 8, 256, 0, stream>>>(
        Z1, (const float*)d_in[8], (const float*)d_in[9],
        (const float*)d_in[10], (const float*)d_in[11], Z0, Q, K, V);
    attn_big<10, 12, 1, 2><<<96 * 4, 256, 13312, stream>>>(
        Q, K, V, (const float*)d_in[14], O, 256, 4, 961, SC10);
    outproj<<<1024, 256, 0, stream>>>(
        O, (const float*)d_in[12], (const float*)d_in[13], Z0, Z1, 32, 30, 256, 10);

    // ===== layer 3: Cin=32 H16->8, dim=64, inner=63, d=21 (DP=24), N=64, Hg=8 =====
    conv_qkv<32, 16, 64, 8, 63, 24, 8><<<32 * 8, 256, 0, stream>>>(
        Z1, (const float*)d_in[15], (const float*)d_in[16],
        (const float*)d_in[17], (const float*)d_in[18], Z0, Q, K, V);
    attn_small<<<96, 256, 0, stream>>>(Q, K, V, (const float*)d_in[21], O, SC21);
    tail<<<32, 256, 0, stream>>>(
        O, (const float*)d_in[19], (const float*)d_in[20], Z0,
        (const float*)d_in[22], (const float*)d_in[23], out);
}